// Round 6
// baseline (52936.139 us; speedup 1.0000x reference)
//
#include <hip/hip_runtime.h>
#include <hip/hip_bf16.h>
#include <stdint.h>

#define T_SEQ 8192
#define DIMS  2048
#define VOCAB 512
#define GS    ((size_t)VOCAB * DIMS)

typedef unsigned short u16;
typedef unsigned int   uint32;
typedef unsigned long long u64;
typedef _Float16 f16;
typedef _Float16 f16x2 __attribute__((ext_vector_type(2)));

__device__ __forceinline__ uint32 pkh2(float a, float b) {
  f16x2 h; h.x = (f16)a; h.y = (f16)b;
  return __builtin_bit_cast(uint32, h);
}
__device__ __forceinline__ f16x2 bch2(uint32 u) { return __builtin_bit_cast(f16x2, u); }
__device__ __forceinline__ float sigm(float x) { return 1.f / (1.f + __expf(-x)); }
__device__ __forceinline__ float tanh_f(float x) { return 1.f - 2.f / (1.f + __expf(2.f * x)); }

// ---------------------------------------------------------------- X = Wx.T + bx
__global__ __launch_bounds__(256) void k_build_x(const float* __restrict__ Wx,
                                                 const float* __restrict__ bx,
                                                 float* __restrict__ X) {
  int i = blockIdx.x * 256 + threadIdx.x;      // i = d*VOCAB + v
  int v = i & (VOCAB - 1);
  int d = i >> 9;
  X[(size_t)v * DIMS + d] = Wx[i] + bx[d];
}

// ---------------------------------------------------------------- G_g = X @ Wg.T + bwg
// Output interleaved by gate: G4[(v*DIMS + j)*4 + gate] -> one float4 per row fetch.
__global__ __launch_bounds__(256) void k_gate_gemm(const float* __restrict__ X,
                                                   const float* __restrict__ Wg,
                                                   const float* __restrict__ bw,
                                                   float* __restrict__ Gout,
                                                   int gate) {
  __shared__ float Xs[32][64];
  __shared__ float Ws[32][64];
  const int v0 = blockIdx.y * 64;
  const int j0 = blockIdx.x * 64;
  const int tid = threadIdx.x;
  const int tx = tid & 15, ty = tid >> 4;
  float acc[4][4] = {{0.f}};
  for (int k0 = 0; k0 < DIMS; k0 += 32) {
    const int r = tid >> 2, q = tid & 3;
    {
      const float* src = X + (size_t)(v0 + r) * DIMS + k0 + q * 8;
      float4 a = ((const float4*)src)[0];
      float4 b = ((const float4*)src)[1];
      Xs[q*8+0][r]=a.x; Xs[q*8+1][r]=a.y; Xs[q*8+2][r]=a.z; Xs[q*8+3][r]=a.w;
      Xs[q*8+4][r]=b.x; Xs[q*8+5][r]=b.y; Xs[q*8+6][r]=b.z; Xs[q*8+7][r]=b.w;
      const float* wsrc = Wg + (size_t)(j0 + r) * DIMS + k0 + q * 8;
      float4 c = ((const float4*)wsrc)[0];
      float4 e = ((const float4*)wsrc)[1];
      Ws[q*8+0][r]=c.x; Ws[q*8+1][r]=c.y; Ws[q*8+2][r]=c.z; Ws[q*8+3][r]=c.w;
      Ws[q*8+4][r]=e.x; Ws[q*8+5][r]=e.y; Ws[q*8+6][r]=e.z; Ws[q*8+7][r]=e.w;
    }
    __syncthreads();
    #pragma unroll
    for (int k = 0; k < 32; ++k) {
      float xa[4], wb[4];
      *(float4*)xa = *(const float4*)&Xs[k][ty*4];
      *(float4*)wb = *(const float4*)&Ws[k][tx*4];
      #pragma unroll
      for (int a = 0; a < 4; ++a)
        #pragma unroll
        for (int b = 0; b < 4; ++b)
          acc[a][b] = fmaf(xa[a], wb[b], acc[a][b]);
    }
    __syncthreads();
  }
  #pragma unroll
  for (int a = 0; a < 4; ++a)
    #pragma unroll
    for (int b = 0; b < 4; ++b)
      Gout[(((size_t)(v0 + ty*4 + a) * DIMS + j0 + tx*4 + b) << 2) + gate] =
          acc[a][b] + bw[j0 + tx*4 + b];
}

// ---------------------------------------------------------------- recurrence
// 256 blocks x 512 threads (8 waves, 2/SIMD). Wave w owns row jr = blk*8+w.
// Lane split: g2 = lane>>5 selects gate pair (f,i) or (c,o); s5 = lane&31 is
// the k-split: chunk c = 32*i + s5 covers h[8c..8c+8), i = 0..7 -> 64 k/lane,
// used for BOTH gates of the pair (halves LDS traffic vs round 5).
// Weights: 64 packed f16x2 per lane in AGPRs (round-5-proven residency).
// Dot: stage all 8 uint4 h-chunks into regs FIRST (compiler pipelines the
// ds_reads - round 5's asm-volatile-interleaved loop serialized them), then
// 64 accvgpr_read + 64 v_dot2_f32_f16.
// Sync: h published f32 with 8-bit step tag in mantissa LSBs + per-block
// epoch counter hint (8th wave via LDS depth-4 ring publishes cnt[blk]=t+1).
// Consumers: optimistic tag-checked read; on miss spin on the 1-line counter,
// then selective reload. Tags are ground truth; counter is only a hint.
__global__ __launch_bounds__(512, 2) void k_lstm(
    const int* __restrict__ tokens,
    const float4* __restrict__ G4,
    uint32* hbuf, uint32* cnt, u16* hs16,
    const float* __restrict__ Uf, const float* __restrict__ Ui,
    const float* __restrict__ Uc, const float* __restrict__ Uo,
    const float* __restrict__ bUf, const float* __restrict__ bUi,
    const float* __restrict__ bUc, const float* __restrict__ bUo) {
  __shared__ uint2 hp[2][512];        // [parity][thread] = 4 h values as f16x4
  __shared__ int tok_lds[T_SEQ];      // 32 KiB
  __shared__ int wdone[4];            // publish-count ring (depth 4: race-safe)
  const int tid  = threadIdx.x;
  const int wave = tid >> 6;
  const int lane = tid & 63;
  const int g2   = lane >> 5;
  const int s5   = lane & 31;
  const int blk  = blockIdx.x;
  const int jr   = blk * 8 + wave;

  for (int i = tid; i < T_SEQ; i += 512) tok_lds[i] = tokens[i];
  if (tid < 4) wdone[tid] = 0;

  // ---- weights -> AGPRs (f16x2 packed; A = gate 2*g2, B = gate 2*g2+1)
  const float* rowA = (g2 ? Uc : Uf) + (size_t)jr * DIMS;
  const float* rowB = (g2 ? Uo : Ui) + (size_t)jr * DIMS;
  float wa[64];
  #pragma unroll
  for (int i = 0; i < 8; ++i) {
    const int c = 32 * i + s5;
    float4 a0 = ((const float4*)rowA)[2*c];
    float4 a1 = ((const float4*)rowA)[2*c+1];
    uint32 p0 = pkh2(a0.x, a0.y), p1 = pkh2(a0.z, a0.w);
    uint32 p2 = pkh2(a1.x, a1.y), p3 = pkh2(a1.z, a1.w);
    asm volatile("v_accvgpr_write_b32 %0, %1" : "=a"(wa[4*i+0]) : "v"(p0));
    asm volatile("v_accvgpr_write_b32 %0, %1" : "=a"(wa[4*i+1]) : "v"(p1));
    asm volatile("v_accvgpr_write_b32 %0, %1" : "=a"(wa[4*i+2]) : "v"(p2));
    asm volatile("v_accvgpr_write_b32 %0, %1" : "=a"(wa[4*i+3]) : "v"(p3));
    float4 b0 = ((const float4*)rowB)[2*c];
    float4 b1 = ((const float4*)rowB)[2*c+1];
    uint32 q0 = pkh2(b0.x, b0.y), q1 = pkh2(b0.z, b0.w);
    uint32 q2 = pkh2(b1.x, b1.y), q3 = pkh2(b1.z, b1.w);
    asm volatile("v_accvgpr_write_b32 %0, %1" : "=a"(wa[32+4*i+0]) : "v"(q0));
    asm volatile("v_accvgpr_write_b32 %0, %1" : "=a"(wa[32+4*i+1]) : "v"(q1));
    asm volatile("v_accvgpr_write_b32 %0, %1" : "=a"(wa[32+4*i+2]) : "v"(q2));
    asm volatile("v_accvgpr_write_b32 %0, %1" : "=a"(wa[32+4*i+3]) : "v"(q3));
  }

  float creg = 0.f, b0r = 0.f, b1r = 0.f;
  float4 gv = make_float4(0.f, 0.f, 0.f, 0.f);
  if (lane == 0) {
    b0r = bUf[jr]; b1r = bUi[jr];
    gv = G4[(size_t)tokens[0] * DIMS + jr];
    __hip_atomic_store(&hbuf[jr], 0u, __ATOMIC_RELAXED, __HIP_MEMORY_SCOPE_AGENT);
    __hip_atomic_store(&hbuf[DIMS + jr], 0u, __ATOMIC_RELAXED, __HIP_MEMORY_SCOPE_AGENT);
    if (wave == 0) __hip_atomic_store(&cnt[blk], 0u, __ATOMIC_RELAXED, __HIP_MEMORY_SCOPE_AGENT);
  } else if (lane == 32) {
    b0r = bUc[jr]; b1r = bUo[jr];
  }
  __syncthreads();   // covers tok_lds / wdone init

  #pragma unroll 1
  for (int t = 0; t < T_SEQ; ++t) {
    const int par = t & 1;
    { // ---- poll + stage h_t (thread owns h[4*tid..4*tid+3])
      const u64* hsrc = (const u64*)(hbuf + (size_t)par * DIMS) + 2 * tid;
      const uint32 want = (uint32)t & 0xFFu;
      u64 u0 = __hip_atomic_load(hsrc + 0, __ATOMIC_RELAXED, __HIP_MEMORY_SCOPE_AGENT);
      u64 u1 = __hip_atomic_load(hsrc + 1, __ATOMIC_RELAXED, __HIP_MEMORY_SCOPE_AGENT);
      bool ok0 = ((((uint32)u0 ^ want) | ((uint32)(u0 >> 32) ^ want)) & 0xFFu) == 0u;
      bool ok1 = ((((uint32)u1 ^ want) | ((uint32)(u1 >> 32) ^ want)) & 0xFFu) == 0u;
      if (!(ok0 && ok1)) {
        const uint32* cp = cnt + (tid >> 1);   // my 4 rows come from ONE producer block
        for (;;) {
          while (__hip_atomic_load(cp, __ATOMIC_RELAXED, __HIP_MEMORY_SCOPE_AGENT) < (uint32)t)
            __builtin_amdgcn_s_sleep(1);
          if (!ok0) {
            u0 = __hip_atomic_load(hsrc + 0, __ATOMIC_RELAXED, __HIP_MEMORY_SCOPE_AGENT);
            ok0 = ((((uint32)u0 ^ want) | ((uint32)(u0 >> 32) ^ want)) & 0xFFu) == 0u;
          }
          if (!ok1) {
            u1 = __hip_atomic_load(hsrc + 1, __ATOMIC_RELAXED, __HIP_MEMORY_SCOPE_AGENT);
            ok1 = ((((uint32)u1 ^ want) | ((uint32)(u1 >> 32) ^ want)) & 0xFFu) == 0u;
          }
          if (ok0 && ok1) break;
          __builtin_amdgcn_s_sleep(1);
        }
      }
      const float f0 = __uint_as_float((uint32)u0), f1 = __uint_as_float((uint32)(u0 >> 32));
      const float f2 = __uint_as_float((uint32)u1), f3 = __uint_as_float((uint32)(u1 >> 32));
      hp[par][tid] = make_uint2(pkh2(f0, f1), pkh2(f2, f3));
    }
    __syncthreads();
    // bulk hs write: block (t&255) writes the staged 4KB h_t, coalesced
    if (((t ^ blk) & 255) == 0)
      ((uint2*)(hs16 + (size_t)t * DIMS))[tid] = hp[par][tid];

    // ---- dot: 2 gates x 64 k per lane; stage LDS reads first, then VALU
    uint4 hh[8];
    const uint4* hc = (const uint4*)&hp[par][0];
    #pragma unroll
    for (int i = 0; i < 8; ++i) hh[i] = hc[32 * i + s5];
    float accA = 0.f, accB = 0.f;
    #pragma unroll
    for (int i = 0; i < 8; ++i) {
      const uint32 h0 = hh[i].x, h1 = hh[i].y, h2 = hh[i].z, h3 = hh[i].w;
      uint32 w0, w1, w2, w3, v0, v1, v2, v3;
      asm volatile("v_accvgpr_read_b32 %0, %1" : "=v"(w0) : "a"(wa[4*i+0]));
      asm volatile("v_accvgpr_read_b32 %0, %1" : "=v"(w1) : "a"(wa[4*i+1]));
      asm volatile("v_accvgpr_read_b32 %0, %1" : "=v"(w2) : "a"(wa[4*i+2]));
      asm volatile("v_accvgpr_read_b32 %0, %1" : "=v"(w3) : "a"(wa[4*i+3]));
      asm volatile("v_accvgpr_read_b32 %0, %1" : "=v"(v0) : "a"(wa[32+4*i+0]));
      asm volatile("v_accvgpr_read_b32 %0, %1" : "=v"(v1) : "a"(wa[32+4*i+1]));
      asm volatile("v_accvgpr_read_b32 %0, %1" : "=v"(v2) : "a"(wa[32+4*i+2]));
      asm volatile("v_accvgpr_read_b32 %0, %1" : "=v"(v3) : "a"(wa[32+4*i+3]));
      accA = __builtin_amdgcn_fdot2(bch2(w0), bch2(h0), accA, false);
      accB = __builtin_amdgcn_fdot2(bch2(v0), bch2(h0), accB, false);
      accA = __builtin_amdgcn_fdot2(bch2(w1), bch2(h1), accA, false);
      accB = __builtin_amdgcn_fdot2(bch2(v1), bch2(h1), accB, false);
      accA = __builtin_amdgcn_fdot2(bch2(w2), bch2(h2), accA, false);
      accB = __builtin_amdgcn_fdot2(bch2(v2), bch2(h2), accB, false);
      accA = __builtin_amdgcn_fdot2(bch2(w3), bch2(h3), accA, false);
      accB = __builtin_amdgcn_fdot2(bch2(v3), bch2(h3), accB, false);
    }
    // reduce over 32 lanes (each half-wave reduces independently)
    #pragma unroll
    for (int d = 1; d <= 16; d <<= 1) {
      accA += __shfl_xor(accA, d, 64);
      accB += __shfl_xor(accB, d, 64);
    }
    // lane 0 now has (f,i) sums; lane 32 has (c,o) sums
    const float gz = __shfl(gv.z, 0, 64);
    const float gw = __shfl(gv.w, 0, 64);
    float e0 = 0.f, e1 = 0.f;
    if (lane == 32) {
      e0 = tanh_f(accA + b0r + gz);   // c_new
      e1 = sigm(accB + b1r + gw);     // o gate
    }
    const float cn = __shfl(e0, 32, 64);
    const float og = __shfl(e1, 32, 64);
    if (lane == 0) {
      const float fg = sigm(accA + b0r + gv.x);
      const float ig = sigm(accB + b1r + gv.y);
      creg = fg * creg + ig * cn;
      const float hv = og * tanh_f(creg);
      const uint32 tb = (__float_as_uint(hv) & 0xFFFFFF00u) | ((uint32)(t + 1) & 0xFFu);
      __hip_atomic_store(&hbuf[(size_t)((t + 1) & 1) * DIMS + jr], tb,
                         __ATOMIC_RELAXED, __HIP_MEMORY_SCOPE_AGENT);
      const int old = atomicAdd(&wdone[(t + 1) & 3], 1);
      if (old == 7) {
        wdone[(t + 3) & 3] = 0;
        __hip_atomic_store(&cnt[blk], (uint32)(t + 1), __ATOMIC_RELAXED, __HIP_MEMORY_SCOPE_AGENT);
      }
      const int tn = (t + 1 < T_SEQ) ? t + 1 : T_SEQ - 1;
      gv = G4[(size_t)tok_lds[tn] * DIMS + jr];   // prefetch gates for t+1
    }
  }
}

// ---------------------------------------------------------------- logits = hs @ V.T + bv
__device__ __forceinline__ void load8f(const float* p, float* o) {
  float4 a = ((const float4*)p)[0], b = ((const float4*)p)[1];
  o[0]=a.x; o[1]=a.y; o[2]=a.z; o[3]=a.w; o[4]=b.x; o[5]=b.y; o[6]=b.z; o[7]=b.w;
}
__device__ __forceinline__ void load8h(const u16* p, float* o) {
  uint4 u = *(const uint4*)p;
  f16x2 a = bch2(u.x), b = bch2(u.y), c = bch2(u.z), d = bch2(u.w);
  o[0]=(float)a.x; o[1]=(float)a.y; o[2]=(float)b.x; o[3]=(float)b.y;
  o[4]=(float)c.x; o[5]=(float)c.y; o[6]=(float)d.x; o[7]=(float)d.y;
}

__global__ __launch_bounds__(256) void k_out_gemm(const u16* __restrict__ hs,
                                                  const float* __restrict__ V,
                                                  const float* __restrict__ bvb,
                                                  float* __restrict__ logits) {
  __shared__ float As[32][64];
  __shared__ float Bs[32][128];
  const int t0 = blockIdx.x * 64;
  const int v0 = blockIdx.y * 128;
  const int tid = threadIdx.x;
  const int tx = tid & 15, ty = tid >> 4;
  float acc[4][8] = {{0.f}};
  for (int k0 = 0; k0 < DIMS; k0 += 32) {
    {
      const int r = tid >> 2, q = tid & 3;
      float o8[8];
      load8h(hs + (size_t)(t0 + r) * DIMS + k0 + q * 8, o8);
      #pragma unroll
      for (int s = 0; s < 8; ++s) As[q*8+s][r] = o8[s];
      const int rb = tid >> 1, c0 = (tid & 1) * 2;
      #pragma unroll
      for (int c = 0; c < 2; ++c) {
        float p8[8];
        load8f(V + (size_t)(v0 + rb) * DIMS + k0 + (c0 + c) * 8, p8);
        #pragma unroll
        for (int s = 0; s < 8; ++s) Bs[(c0+c)*8+s][rb] = p8[s];
      }
    }
    __syncthreads();
    #pragma unroll
    for (int k = 0; k < 32; ++k) {
      float av[4], bw8[8];
      *(float4*)av = *(const float4*)&As[k][ty*4];
      *(float4*)&bw8[0] = *(const float4*)&Bs[k][tx*8];
      *(float4*)&bw8[4] = *(const float4*)&Bs[k][tx*8+4];
      #pragma unroll
      for (int a = 0; a < 4; ++a)
        #pragma unroll
        for (int b = 0; b < 8; ++b)
          acc[a][b] = fmaf(av[a], bw8[b], acc[a][b]);
    }
    __syncthreads();
  }
  #pragma unroll
  for (int a = 0; a < 4; ++a)
    #pragma unroll
    for (int b = 0; b < 8; ++b)
      logits[(size_t)(t0 + ty*4 + a) * VOCAB + v0 + tx*8 + b] =
          acc[a][b] + bvb[v0 + tx*8 + b];
}

// ---------------------------------------------------------------- log_softmax rows (in-place)
__global__ __launch_bounds__(256) void k_logsoftmax(float* __restrict__ logits) {
  const int t = blockIdx.x;
  const int tid = threadIdx.x;
  float* row = logits + (size_t)t * VOCAB;
  float x0 = row[tid], x1 = row[tid + 256];
  float m = fmaxf(x0, x1);
  #pragma unroll
  for (int d = 32; d; d >>= 1) m = fmaxf(m, __shfl_xor(m, d, 64));
  __shared__ float r1[4], r2[4];
  if ((tid & 63) == 0) r1[tid >> 6] = m;
  __syncthreads();
  m = fmaxf(fmaxf(r1[0], r1[1]), fmaxf(r1[2], r1[3]));
  float s = __expf(x0 - m) + __expf(x1 - m);
  #pragma unroll
  for (int d = 32; d; d >>= 1) s += __shfl_xor(s, d, 64);
  if ((tid & 63) == 0) r2[tid >> 6] = s;
  __syncthreads();
  s = r2[0] + r2[1] + r2[2] + r2[3];
  const float lse = m + __logf(s);
  row[tid] = x0 - lse;
  row[tid + 256] = x1 - lse;
}

// ----------------------------------------------------------------
extern "C" void kernel_launch(void* const* d_in, const int* in_sizes, int n_in,
                              void* d_out, int out_size, void* d_ws, size_t ws_size,
                              hipStream_t stream) {
  const int*   tokens = (const int*)d_in[0];
  const float* Wx  = (const float*)d_in[1];
  const float* bx  = (const float*)d_in[2];
  const float* Uf  = (const float*)d_in[3];
  const float* bUf = (const float*)d_in[4];
  const float* Wf  = (const float*)d_in[5];
  const float* bwf = (const float*)d_in[6];
  const float* Ui  = (const float*)d_in[7];
  const float* bUi = (const float*)d_in[8];
  const float* Wi  = (const float*)d_in[9];
  const float* bwi = (const float*)d_in[10];
  const float* Uc  = (const float*)d_in[11];
  const float* bUc = (const float*)d_in[12];
  const float* Wc  = (const float*)d_in[13];
  const float* bwc = (const float*)d_in[14];
  const float* Uo  = (const float*)d_in[15];
  const float* bUo = (const float*)d_in[16];
  const float* Wo  = (const float*)d_in[17];
  const float* bwo = (const float*)d_in[18];
  const float* V   = (const float*)d_in[19];
  const float* bv  = (const float*)d_in[20];

  char* ws = (char*)d_ws;
  float*  X    = (float*)ws;                         // 4 MiB @ 0
  float*  G    = (float*)(ws + 4194304ull);          // 16 MiB (gate-interleaved)
  uint32* hbuf = (uint32*)(ws + 20971520ull);        // 16 KiB
  uint32* cnt  = (uint32*)(ws + 20987904ull);        // 1 KiB
  u16*    hs16 = (u16*)(ws + 21004288ull);           // 32 MiB (f16)

  k_build_x<<<dim3((DIMS * VOCAB) / 256), dim3(256), 0, stream>>>(Wx, bx, X);
  dim3 gg(DIMS / 64, VOCAB / 64);
  k_gate_gemm<<<gg, dim3(256), 0, stream>>>(X, Wf, bwf, G, 0);
  k_gate_gemm<<<gg, dim3(256), 0, stream>>>(X, Wi, bwi, G, 1);
  k_gate_gemm<<<gg, dim3(256), 0, stream>>>(X, Wc, bwc, G, 2);
  k_gate_gemm<<<gg, dim3(256), 0, stream>>>(X, Wo, bwo, G, 3);

  float* logits = (float*)d_out;   // logits built in d_out, log_softmax in-place
  k_lstm<<<dim3(256), dim3(512), 0, stream>>>(
      tokens, (const float4*)G, hbuf, cnt, hs16,
      Uf, Ui, Uc, Uo, bUf, bUi, bUc, bUo);
  k_out_gemm<<<dim3(T_SEQ / 64, VOCAB / 128), dim3(256), 0, stream>>>(
      hs16, V, bv, logits);
  k_logsoftmax<<<dim3(T_SEQ), dim3(256), 0, stream>>>(logits);
}